// Round 1
// baseline (54.717 us; speedup 1.0000x reference)
//
#include <hip/hip_runtime.h>

namespace {

constexpr int NCOL  = 3;
constexpr int N_IN  = 4;
constexpr int N_OUT = 8;
constexpr int T_W   = 37;
constexpr int NB    = 4;       // batch
constexpr int NX    = 16384;   // 8*8*16*16 lattice sites
constexpr int MAT   = 2 * NCOL * NCOL;   // 18 floats per complex 3x3
constexpr int NTHREADS = NB * NX * 3;    // one thread per (site, column)

// lattice dims (8,8,16,16): shifts and strides for flattened row-major index
__device__ constexpr int SH[4] = {11, 8, 4, 0};
__device__ constexpr int DD[4] = {8, 8, 16, 16};
__device__ constexpr int SS[4] = {2048, 256, 16, 1};

__device__ __forceinline__ void load_mat(const float* __restrict__ p, float* M) {
#pragma unroll
    for (int k = 0; k < 9; ++k) {
        float2 e = *(const float2*)(p + 2 * k);
        M[2 * k]     = e.x;
        M[2 * k + 1] = e.y;
    }
}

__global__ __launch_bounds__(256) void lconv_kernel(
    const float* __restrict__ u,
    const float* __restrict__ w,
    const float* __restrict__ wgt,
    float* __restrict__ out)
{
    __shared__ float wT[T_W][N_OUT];   // transposed weights: wT[v][uo] = wgt[uo*37+v]
    const int tid = threadIdx.x;
    for (int idx = tid; idx < T_W * N_OUT; idx += 256) {
        int uo = idx & 7;
        int v  = idx >> 3;
        wT[v][uo] = wgt[uo * T_W + v];
    }
    __syncthreads();

    const int gid = blockIdx.x * 256 + tid;

    // ---- fused coalesced copy of u into out[0 : NB*NX*4*MAT) ----
    {
        const float4* __restrict__ u4 = (const float4*)u;
        float4* __restrict__ o4 = (float4*)out;
#pragma unroll
        for (int k = 0; k < 6; ++k) {
            int idx = gid + k * NTHREADS;
            o4[idx] = u4[idx];
        }
    }

    const int j  = gid % 3;        // which matrix column this thread owns
    const int bs = gid / 3;        // b*NX + x
    const int x  = bs & (NX - 1);

    const float* __restrict__ ubase = u + (size_t)bs * (4 * MAT);
    const float* __restrict__ wbase = w + (size_t)bs * (N_IN * MAT);

    float acc[N_OUT][NCOL][2];
#pragma unroll
    for (int uo = 0; uo < N_OUT; ++uo)
#pragma unroll
        for (int i = 0; i < NCOL; ++i) { acc[uo][i][0] = 0.f; acc[uo][i][1] = 0.f; }

    // ---------------- term 0: w itself ----------------
#pragma unroll
    for (int v = 0; v < N_IN; ++v) {
        float cw[N_OUT];
#pragma unroll
        for (int uo = 0; uo < N_OUT; ++uo) cw[uo] = wT[v][uo];
#pragma unroll
        for (int i = 0; i < NCOL; ++i) {
            float2 e = *(const float2*)(wbase + v * MAT + (i * NCOL + j) * 2);
#pragma unroll
            for (int uo = 0; uo < N_OUT; ++uo) {
                acc[uo][i][0] = fmaf(cw[uo], e.x, acc[uo][i][0]);
                acc[uo][i][1] = fmaf(cw[uo], e.y, acc[uo][i][1]);
            }
        }
    }

    // ---------------- transported terms ----------------
#pragma unroll
    for (int a = 0; a < 4; ++a) {
        const int ca = (x >> SH[a]) & (DD[a] - 1);
        const int xp = (ca == DD[a] - 1) ? x - (DD[a] - 1) * SS[a] : x + SS[a];
        const int xm = (ca == 0)         ? x + (DD[a] - 1) * SS[a] : x - SS[a];
        const int bsp = bs - x + xp;
        const int bsm = bs - x + xm;

        // ---- orientation +1:  T = U_a(x) * w(x+e_a) * U_a(x)^H ----
        {
            const float* __restrict__ Up = ubase + a * MAT;
            float U[MAT];
            load_mat(Up, U);
            // d = conj(row j of U)  (column j of U^H)
            float vr[3], vi[3];
#pragma unroll
            for (int k = 0; k < 3; ++k) {
                float2 e = *(const float2*)(Up + (j * NCOL + k) * 2);
                vr[k] = e.x;
                vi[k] = -e.y;
            }
            const float* __restrict__ wn = w + (size_t)bsp * (N_IN * MAT);
            for (int v = 0; v < N_IN; ++v) {
                float Wn[MAT];
                load_mat(wn + v * MAT, Wn);
                // y = Wn * d
                float yr[3], yi[3];
#pragma unroll
                for (int i = 0; i < NCOL; ++i) {
                    float sr = 0.f, si = 0.f;
#pragma unroll
                    for (int k = 0; k < NCOL; ++k) {
                        float wr = Wn[(i * NCOL + k) * 2];
                        float wi = Wn[(i * NCOL + k) * 2 + 1];
                        sr = fmaf(wr, vr[k], sr); sr = fmaf(-wi, vi[k], sr);
                        si = fmaf(wr, vi[k], si); si = fmaf(wi, vr[k], si);
                    }
                    yr[i] = sr; yi[i] = si;
                }
                // col = U * y
                float cr[3], ci[3];
#pragma unroll
                for (int i = 0; i < NCOL; ++i) {
                    float sr = 0.f, si = 0.f;
#pragma unroll
                    for (int k = 0; k < NCOL; ++k) {
                        float ur = U[(i * NCOL + k) * 2];
                        float ui = U[(i * NCOL + k) * 2 + 1];
                        sr = fmaf(ur, yr[k], sr); sr = fmaf(-ui, yi[k], sr);
                        si = fmaf(ur, yi[k], si); si = fmaf(ui, yr[k], si);
                    }
                    cr[i] = sr; ci[i] = si;
                }
                float cw[N_OUT];
#pragma unroll
                for (int uo = 0; uo < N_OUT; ++uo) cw[uo] = wT[(1 + a) * 4 + v][uo];
#pragma unroll
                for (int uo = 0; uo < N_OUT; ++uo)
#pragma unroll
                    for (int i = 0; i < NCOL; ++i) {
                        acc[uo][i][0] = fmaf(cw[uo], cr[i], acc[uo][i][0]);
                        acc[uo][i][1] = fmaf(cw[uo], ci[i], acc[uo][i][1]);
                    }
            }
        }

        // ---- orientation -1:  T = U_a(x-e_a)^H * w(x-e_a) * U_a(x-e_a) ----
        {
            const float* __restrict__ Um = u + (size_t)bsm * (4 * MAT) + a * MAT;
            float U[MAT];
            load_mat(Um, U);
            // d = column j of U~ (no conj)
            float vr[3], vi[3];
#pragma unroll
            for (int k = 0; k < 3; ++k) {
                float2 e = *(const float2*)(Um + (k * NCOL + j) * 2);
                vr[k] = e.x;
                vi[k] = e.y;
            }
            const float* __restrict__ wn = w + (size_t)bsm * (N_IN * MAT);
            for (int v = 0; v < N_IN; ++v) {
                float Wn[MAT];
                load_mat(wn + v * MAT, Wn);
                // y = Wn * d
                float yr[3], yi[3];
#pragma unroll
                for (int i = 0; i < NCOL; ++i) {
                    float sr = 0.f, si = 0.f;
#pragma unroll
                    for (int k = 0; k < NCOL; ++k) {
                        float wr = Wn[(i * NCOL + k) * 2];
                        float wi = Wn[(i * NCOL + k) * 2 + 1];
                        sr = fmaf(wr, vr[k], sr); sr = fmaf(-wi, vi[k], sr);
                        si = fmaf(wr, vi[k], si); si = fmaf(wi, vr[k], si);
                    }
                    yr[i] = sr; yi[i] = si;
                }
                // col_i = sum_k conj(U~[k][i]) * y_k
                float cr[3], ci[3];
#pragma unroll
                for (int i = 0; i < NCOL; ++i) {
                    float sr = 0.f, si = 0.f;
#pragma unroll
                    for (int k = 0; k < NCOL; ++k) {
                        float ur = U[(k * NCOL + i) * 2];
                        float ui = U[(k * NCOL + i) * 2 + 1];
                        sr = fmaf(ur, yr[k], sr); sr = fmaf(ui, yi[k], sr);
                        si = fmaf(ur, yi[k], si); si = fmaf(-ui, yr[k], si);
                    }
                    cr[i] = sr; ci[i] = si;
                }
                float cw[N_OUT];
#pragma unroll
                for (int uo = 0; uo < N_OUT; ++uo) cw[uo] = wT[(5 + a) * 4 + v][uo];
#pragma unroll
                for (int uo = 0; uo < N_OUT; ++uo)
#pragma unroll
                    for (int i = 0; i < NCOL; ++i) {
                        acc[uo][i][0] = fmaf(cw[uo], cr[i], acc[uo][i][0]);
                        acc[uo][i][1] = fmaf(cw[uo], ci[i], acc[uo][i][1]);
                    }
            }
        }
    }

    // ---------------- store (fold in identity term, channel 36) ----------------
    float cid[N_OUT];
#pragma unroll
    for (int uo = 0; uo < N_OUT; ++uo) cid[uo] = wT[36][uo];

    float* __restrict__ obase = out + (size_t)NB * NX * 4 * MAT + (size_t)bs * (N_OUT * MAT);
#pragma unroll
    for (int uo = 0; uo < N_OUT; ++uo)
#pragma unroll
        for (int i = 0; i < NCOL; ++i) {
            float2 e;
            e.x = acc[uo][i][0] + ((i == j) ? cid[uo] : 0.f);
            e.y = acc[uo][i][1];
            *(float2*)(obase + uo * MAT + (i * NCOL + j) * 2) = e;
        }
}

} // namespace

extern "C" void kernel_launch(void* const* d_in, const int* in_sizes, int n_in,
                              void* d_out, int out_size, void* d_ws, size_t ws_size,
                              hipStream_t stream)
{
    const float* u   = (const float*)d_in[0];
    const float* w   = (const float*)d_in[1];
    const float* wgt = (const float*)d_in[2];
    float* out = (float*)d_out;

    dim3 block(256);
    dim3 grid(NTHREADS / 256);   // 768 blocks, exact cover
    lconv_kernel<<<grid, block, 0, stream>>>(u, w, wgt, out);
}